// Round 1
// baseline (1659.200 us; speedup 1.0000x reference)
//
#include <hip/hip_runtime.h>
#include <stdint.h>

#define D_MODEL 1024
#define NHEAD   16
#define DEPTH   64
#define BATCH   2
#define SEQ     2048
#define M_ROWS  (BATCH*SEQ)   // 4096

typedef __attribute__((ext_vector_type(8))) short short8;
typedef __attribute__((ext_vector_type(4))) float f32x4;

// float -> bf16 bits, round-to-nearest-even (inputs are finite; no NaN path needed)
__device__ __forceinline__ unsigned short f2b(float f) {
    union { float f; uint32_t u; } v; v.f = f;
    uint32_t r = (v.u + 0x7FFFu + ((v.u >> 16) & 1u)) >> 16;
    return (unsigned short)r;
}

// ---------------------------------------------------------------- cast fp32 -> bf16
__global__ __launch_bounds__(256) void cast3_bf16(
    const float* __restrict__ s0, const float* __restrict__ s1, const float* __restrict__ s2,
    unsigned short* __restrict__ d0, unsigned short* __restrict__ d1, unsigned short* __restrict__ d2)
{
    const float* s; unsigned short* d;
    if (blockIdx.y == 0)      { s = s0; d = d0; }
    else if (blockIdx.y == 1) { s = s1; d = d1; }
    else                      { s = s2; d = d2; }
    int i = blockIdx.x * 256 + threadIdx.x;          // float4 index; grid sized exactly
    float4 v = ((const float4*)s)[i];
    ushort4 u;
    u.x = f2b(v.x); u.y = f2b(v.y); u.z = f2b(v.z); u.w = f2b(v.w);
    ((ushort4*)d)[i] = u;
}

// ---------------------------------------------------------------- W[k][n] -> Wt[n][k] (bf16)
__global__ __launch_bounds__(256) void transpose_w(
    const float* __restrict__ w0, const float* __restrict__ w1,
    const float* __restrict__ w2, const float* __restrict__ w3,
    unsigned short* __restrict__ t0, unsigned short* __restrict__ t1,
    unsigned short* __restrict__ t2, unsigned short* __restrict__ t3)
{
    __shared__ unsigned short tile[64][65];          // +1 pad breaks bank collisions
    const float* w; unsigned short* t;
    switch (blockIdx.z) {
        case 0:  w = w0; t = t0; break;
        case 1:  w = w1; t = t1; break;
        case 2:  w = w2; t = t2; break;
        default: w = w3; t = t3; break;
    }
    const int k0 = blockIdx.y * 64;   // input-dim block
    const int n0 = blockIdx.x * 64;   // output-dim block
    const int tid = threadIdx.x;
    #pragma unroll
    for (int i = 0; i < 16; ++i) {
        int idx = i * 256 + tid;
        int r = idx >> 6, c = idx & 63;
        tile[c][r] = f2b(w[(size_t)(k0 + r) * D_MODEL + n0 + c]);  // coalesced in c
    }
    __syncthreads();
    #pragma unroll
    for (int i = 0; i < 16; ++i) {
        int idx = i * 256 + tid;
        int r = idx >> 6, c = idx & 63;
        t[(size_t)(n0 + r) * D_MODEL + k0 + c] = tile[r][c];       // coalesced in c
    }
}

// ---------------------------------------------------------------- bf16 MFMA GEMM, NT form
// C[m][n] = sum_k A[m][k] * Bt[n][k] + bias[n]
// 128x128 C-tile / block, 4 waves in 2x2, each wave 64x64 = 4x4 MFMA frags (m97 structure).
// Verified layouts (16x16x32 bf16): A/B frag elem j at [m|n = lane&15][k = (lane>>4)*8 + j];
// C/D: col = lane&15, row = (lane>>4)*4 + reg.
template<bool OUT_BF16>
__global__ __launch_bounds__(256) void gemm_bt(
    const unsigned short* __restrict__ A,   // [M,K] bf16
    const unsigned short* __restrict__ Bt,  // [N,K] bf16
    const float* __restrict__ bias,         // [N] fp32
    void* __restrict__ Cv, int M, int N, int K)
{
    __shared__ __align__(16) unsigned short As[128 * 32];
    __shared__ __align__(16) unsigned short Bs[128 * 32];
    const int tid  = threadIdx.x;
    const int lane = tid & 63;
    const int wave = tid >> 6;
    const int wm = wave & 1, wn = wave >> 1;
    const int quad = lane >> 4, l16 = lane & 15;
    const int m0 = blockIdx.y * 128, n0 = blockIdx.x * 128;

    f32x4 acc[4][4] = {};

    float bn[4];
    #pragma unroll
    for (int nt = 0; nt < 4; ++nt) bn[nt] = bias[n0 + wn * 64 + nt * 16 + l16];

    for (int k0 = 0; k0 < K; k0 += 32) {
        // stage: each tile = 512 x 16B chunks; 2 per thread; [row][32] bf16 layout in LDS
        #pragma unroll
        for (int i = 0; i < 2; ++i) {
            int c = i * 256 + tid;
            int row = c >> 2, cb = c & 3;
            ((uint4*)As)[c] = *(const uint4*)(A  + (size_t)(m0 + row) * K + k0 + cb * 8);
            ((uint4*)Bs)[c] = *(const uint4*)(Bt + (size_t)(n0 + row) * K + k0 + cb * 8);
        }
        __syncthreads();
        short8 af[4], bg[4];
        #pragma unroll
        for (int t = 0; t < 4; ++t) {
            af[t] = *(const short8*)&As[(wm * 64 + t * 16 + l16) * 32 + quad * 8];
            bg[t] = *(const short8*)&Bs[(wn * 64 + t * 16 + l16) * 32 + quad * 8];
        }
        #pragma unroll
        for (int mt = 0; mt < 4; ++mt)
            #pragma unroll
            for (int nt = 0; nt < 4; ++nt)
                acc[mt][nt] = __builtin_amdgcn_mfma_f32_16x16x32_bf16(af[mt], bg[nt], acc[mt][nt], 0, 0, 0);
        __syncthreads();
    }

    #pragma unroll
    for (int mt = 0; mt < 4; ++mt) {
        #pragma unroll
        for (int nt = 0; nt < 4; ++nt) {
            #pragma unroll
            for (int r = 0; r < 4; ++r) {
                int m = m0 + wm * 64 + mt * 16 + quad * 4 + r;
                int n = n0 + wn * 64 + nt * 16 + l16;
                float val = acc[mt][nt][r] + bn[nt];
                if (OUT_BF16) ((unsigned short*)Cv)[(size_t)m * N + n] = f2b(val);
                else          ((float*)Cv)[(size_t)m * N + n] = val;
            }
        }
    }
}

// ---------------------------------------------------------------- vector fp32 flash attention
// 1 q-row per thread; K/V tiles (64 keys) staged fp32 in LDS; per-thread online softmax.
// LDS reads inside the key loop are same-address across the wave -> broadcast, conflict-free.
__global__ __launch_bounds__(128) void attn_vec(
    const float* __restrict__ Qf, const float* __restrict__ Kf,
    const float* __restrict__ Vf, unsigned short* __restrict__ ctx)
{
    __shared__ __align__(16) float Ks[64 * 64];
    __shared__ __align__(16) float Vs[64 * 64];
    const int tid = threadIdx.x;
    const int b = blockIdx.z, h = blockIdx.y;
    const int q = blockIdx.x * 128 + tid;

    const float* qrow = Qf + ((size_t)(b * SEQ + q)) * D_MODEL + h * DEPTH;
    float qr[64];
    #pragma unroll
    for (int i = 0; i < 16; ++i) {
        float4 v = *(const float4*)(qrow + 4 * i);
        qr[4 * i] = v.x; qr[4 * i + 1] = v.y; qr[4 * i + 2] = v.z; qr[4 * i + 3] = v.w;
    }

    float mx = -1e30f, l = 0.f;
    float o[64];
    #pragma unroll
    for (int d = 0; d < 64; ++d) o[d] = 0.f;

    const size_t headoff = (size_t)b * SEQ * D_MODEL + h * DEPTH;
    for (int kt = 0; kt < SEQ / 64; ++kt) {
        const float* kb = Kf + headoff + (size_t)kt * 64 * D_MODEL;
        const float* vb = Vf + headoff + (size_t)kt * 64 * D_MODEL;
        #pragma unroll
        for (int i = 0; i < 8; ++i) {
            int idx = i * 128 + tid;            // 1024 float4 chunks per 64x64 tile
            int r = idx >> 4, c4 = idx & 15;
            *(float4*)&Ks[r * 64 + c4 * 4] = *(const float4*)(kb + (size_t)r * D_MODEL + c4 * 4);
            *(float4*)&Vs[r * 64 + c4 * 4] = *(const float4*)(vb + (size_t)r * D_MODEL + c4 * 4);
        }
        __syncthreads();

        for (int kk = 0; kk < 64; ++kk) {
            const float* krow = &Ks[kk * 64];
            float s0 = 0.f, s1 = 0.f, s2 = 0.f, s3 = 0.f;   // 4 chains for ILP
            #pragma unroll
            for (int d = 0; d < 64; d += 4) {
                s0 += qr[d + 0] * krow[d + 0];
                s1 += qr[d + 1] * krow[d + 1];
                s2 += qr[d + 2] * krow[d + 2];
                s3 += qr[d + 3] * krow[d + 3];
            }
            float s = ((s0 + s1) + (s2 + s3)) * 0.125f;     // 1/sqrt(64)
            if (s > mx) {                                   // rare after warm-up
                float alpha = __expf(mx - s);               // mx=-1e30 first hit -> alpha=0
                l *= alpha;
                #pragma unroll
                for (int d = 0; d < 64; ++d) o[d] *= alpha;
                mx = s;
            }
            float p = __expf(s - mx);
            l += p;
            const float* vrow = &Vs[kk * 64];
            #pragma unroll
            for (int d = 0; d < 64; ++d) o[d] += p * vrow[d];
        }
        __syncthreads();
    }

    float inv = 1.0f / l;
    unsigned short* outp = ctx + ((size_t)(b * SEQ + q)) * D_MODEL + h * DEPTH;
    #pragma unroll
    for (int i = 0; i < 16; ++i) {
        ushort4 u;
        u.x = f2b(o[4 * i + 0] * inv);
        u.y = f2b(o[4 * i + 1] * inv);
        u.z = f2b(o[4 * i + 2] * inv);
        u.w = f2b(o[4 * i + 3] * inv);
        *(ushort4*)(outp + 4 * i) = u;
    }
}

// ---------------------------------------------------------------- launch
extern "C" void kernel_launch(void* const* d_in, const int* in_sizes, int n_in,
                              void* d_out, int out_size, void* d_ws, size_t ws_size,
                              hipStream_t stream)
{
    const float* query = (const float*)d_in[0];
    const float* key   = (const float*)d_in[1];
    const float* value = (const float*)d_in[2];
    const float* Wq = (const float*)d_in[3];
    const float* bq = (const float*)d_in[4];
    const float* Wk = (const float*)d_in[5];
    const float* bk = (const float*)d_in[6];
    const float* Wv = (const float*)d_in[7];
    const float* bv = (const float*)d_in[8];
    const float* Wo = (const float*)d_in[9];
    const float* bo = (const float*)d_in[10];

    char* ws = (char*)d_ws;
    size_t off = 0;
    auto alloc = [&](size_t bytes) -> char* {
        char* p = ws + off;
        off += (bytes + 255) & ~(size_t)255;
        return p;
    };
    const size_t xn  = (size_t)M_ROWS * D_MODEL;       // 4M elems
    unsigned short* xq  = (unsigned short*)alloc(xn * 2);
    unsigned short* xk  = (unsigned short*)alloc(xn * 2);
    unsigned short* xv  = (unsigned short*)alloc(xn * 2);
    unsigned short* wqT = (unsigned short*)alloc((size_t)D_MODEL * D_MODEL * 2);
    unsigned short* wkT = (unsigned short*)alloc((size_t)D_MODEL * D_MODEL * 2);
    unsigned short* wvT = (unsigned short*)alloc((size_t)D_MODEL * D_MODEL * 2);
    unsigned short* woT = (unsigned short*)alloc((size_t)D_MODEL * D_MODEL * 2);
    float* Qf = (float*)alloc(xn * 4);
    float* Kf = (float*)alloc(xn * 4);
    float* Vf = (float*)alloc(xn * 4);
    unsigned short* ctx = (unsigned short*)alloc(xn * 2);
    if (off > ws_size) return;   // workspace too small: fail cleanly

    // 1. cast activations fp32 -> bf16 (1,048,576 float4 per tensor)
    cast3_bf16<<<dim3(4096, 3), 256, 0, stream>>>(query, key, value, xq, xk, xv);
    // 2. transpose + cast the 4 weight matrices
    transpose_w<<<dim3(16, 16, 4), 256, 0, stream>>>(Wq, Wk, Wv, Wo, wqT, wkT, wvT, woT);
    // 3. QKV projections (fp32 out for an accurate score path)
    gemm_bt<false><<<dim3(8, 32), 256, 0, stream>>>(xq, wqT, bq, Qf, M_ROWS, D_MODEL, D_MODEL);
    gemm_bt<false><<<dim3(8, 32), 256, 0, stream>>>(xk, wkT, bk, Kf, M_ROWS, D_MODEL, D_MODEL);
    gemm_bt<false><<<dim3(8, 32), 256, 0, stream>>>(xv, wvT, bv, Vf, M_ROWS, D_MODEL, D_MODEL);
    // 4. attention -> bf16 context
    attn_vec<<<dim3(SEQ / 128, NHEAD, BATCH), 128, 0, stream>>>(Qf, Kf, Vf, ctx);
    // 5. output projection -> fp32 d_out
    gemm_bt<false><<<dim3(8, 32), 256, 0, stream>>>(ctx, woT, bo, (float*)d_out, M_ROWS, D_MODEL, D_MODEL);
}

// Round 2
// 280.162 us; speedup vs baseline: 5.9223x; 5.9223x over previous
//
#include <hip/hip_runtime.h>
#include <stdint.h>

#define D_MODEL 1024
#define NHEAD   16
#define DEPTH   64
#define BATCH   2
#define SEQ     2048
#define M_ROWS  (BATCH*SEQ)   // 4096

typedef __attribute__((ext_vector_type(8))) short short8;
typedef __attribute__((ext_vector_type(4))) float f32x4;

// float -> bf16 bits, round-to-nearest-even
__device__ __forceinline__ unsigned short f2b(float f) {
    union { float f; uint32_t u; } v; v.f = f;
    uint32_t r = (v.u + 0x7FFFu + ((v.u >> 16) & 1u)) >> 16;
    return (unsigned short)r;
}

// ---------------------------------------------------------------- cast fp32 -> bf16
__global__ __launch_bounds__(256) void cast3_bf16(
    const float* __restrict__ s0, const float* __restrict__ s1, const float* __restrict__ s2,
    unsigned short* __restrict__ d0, unsigned short* __restrict__ d1, unsigned short* __restrict__ d2)
{
    const float* s; unsigned short* d;
    if (blockIdx.y == 0)      { s = s0; d = d0; }
    else if (blockIdx.y == 1) { s = s1; d = d1; }
    else                      { s = s2; d = d2; }
    int i = blockIdx.x * 256 + threadIdx.x;
    float4 v = ((const float4*)s)[i];
    ushort4 u;
    u.x = f2b(v.x); u.y = f2b(v.y); u.z = f2b(v.z); u.w = f2b(v.w);
    ((ushort4*)d)[i] = u;
}

// ---------------------------------------------------------------- W[k][n] -> Wt[n][k] (bf16)
__global__ __launch_bounds__(256) void transpose_w(
    const float* __restrict__ w0, const float* __restrict__ w1,
    const float* __restrict__ w2, const float* __restrict__ w3,
    unsigned short* __restrict__ t0, unsigned short* __restrict__ t1,
    unsigned short* __restrict__ t2, unsigned short* __restrict__ t3)
{
    __shared__ unsigned short tile[64][65];
    const float* w; unsigned short* t;
    switch (blockIdx.z) {
        case 0:  w = w0; t = t0; break;
        case 1:  w = w1; t = t1; break;
        case 2:  w = w2; t = t2; break;
        default: w = w3; t = t3; break;
    }
    const int k0 = blockIdx.y * 64;
    const int n0 = blockIdx.x * 64;
    const int tid = threadIdx.x;
    #pragma unroll
    for (int i = 0; i < 16; ++i) {
        int idx = i * 256 + tid;
        int r = idx >> 6, c = idx & 63;
        tile[c][r] = f2b(w[(size_t)(k0 + r) * D_MODEL + n0 + c]);
    }
    __syncthreads();
    #pragma unroll
    for (int i = 0; i < 16; ++i) {
        int idx = i * 256 + tid;
        int r = idx >> 6, c = idx & 63;
        t[(size_t)(n0 + r) * D_MODEL + k0 + c] = tile[r][c];
    }
}

// ---------------------------------------------------------------- MFMA GEMM body (NT)
// Verified layouts (16x16x32 bf16): A/B frag elem j at [m|n = lane&15][k = (lane>>4)*8 + j];
// C/D: col = lane&15, row = (lane>>4)*4 + reg.
template<bool OUT_BF16>
__device__ __forceinline__ void gemm_body(
    const unsigned short* __restrict__ A, const unsigned short* __restrict__ Bt,
    const float* __restrict__ bias, void* __restrict__ Cv, int M, int N, int K,
    unsigned short* As, unsigned short* Bs)
{
    const int tid  = threadIdx.x;
    const int lane = tid & 63;
    const int wave = tid >> 6;
    const int wm = wave & 1, wn = wave >> 1;
    const int quad = lane >> 4, l16 = lane & 15;
    const int m0 = blockIdx.y * 128, n0 = blockIdx.x * 128;

    f32x4 acc[4][4] = {};
    float bn[4];
    #pragma unroll
    for (int nt = 0; nt < 4; ++nt) bn[nt] = bias[n0 + wn * 64 + nt * 16 + l16];

    for (int k0 = 0; k0 < K; k0 += 32) {
        #pragma unroll
        for (int i = 0; i < 2; ++i) {
            int c = i * 256 + tid;
            int row = c >> 2, cb = c & 3;
            ((uint4*)As)[c] = *(const uint4*)(A  + (size_t)(m0 + row) * K + k0 + cb * 8);
            ((uint4*)Bs)[c] = *(const uint4*)(Bt + (size_t)(n0 + row) * K + k0 + cb * 8);
        }
        __syncthreads();
        short8 af[4], bg[4];
        #pragma unroll
        for (int t = 0; t < 4; ++t) {
            af[t] = *(const short8*)&As[(wm * 64 + t * 16 + l16) * 32 + quad * 8];
            bg[t] = *(const short8*)&Bs[(wn * 64 + t * 16 + l16) * 32 + quad * 8];
        }
        #pragma unroll
        for (int mt = 0; mt < 4; ++mt)
            #pragma unroll
            for (int nt = 0; nt < 4; ++nt)
                acc[mt][nt] = __builtin_amdgcn_mfma_f32_16x16x32_bf16(af[mt], bg[nt], acc[mt][nt], 0, 0, 0);
        __syncthreads();
    }

    #pragma unroll
    for (int mt = 0; mt < 4; ++mt)
        #pragma unroll
        for (int nt = 0; nt < 4; ++nt)
            #pragma unroll
            for (int r = 0; r < 4; ++r) {
                int m = m0 + wm * 64 + mt * 16 + quad * 4 + r;
                int n = n0 + wn * 64 + nt * 16 + l16;
                float val = acc[mt][nt][r] + bn[nt];
                if (OUT_BF16) ((unsigned short*)Cv)[(size_t)m * N + n] = f2b(val);
                else          ((float*)Cv)[(size_t)m * N + n] = val;
            }
}

// batched QKV projection: blockIdx.z selects (input, weight slice, bias, output)
__global__ __launch_bounds__(256) void gemm_qkv(
    const unsigned short* __restrict__ xq, const unsigned short* __restrict__ xk,
    const unsigned short* __restrict__ xv, const unsigned short* __restrict__ wT,
    const float* __restrict__ bq, const float* __restrict__ bk, const float* __restrict__ bv,
    unsigned short* __restrict__ Qb, unsigned short* __restrict__ Kb, unsigned short* __restrict__ Vb)
{
    __shared__ __align__(16) unsigned short As[128 * 32];
    __shared__ __align__(16) unsigned short Bs[128 * 32];
    const int z = blockIdx.z;
    const unsigned short* A  = (z == 0) ? xq : (z == 1) ? xk : xv;
    const unsigned short* Bt = wT + (size_t)z * D_MODEL * D_MODEL;
    const float* bias        = (z == 0) ? bq : (z == 1) ? bk : bv;
    unsigned short* C        = (z == 0) ? Qb : (z == 1) ? Kb : Vb;
    gemm_body<true>(A, Bt, bias, C, M_ROWS, D_MODEL, D_MODEL, As, Bs);
}

__global__ __launch_bounds__(256) void gemm_out(
    const unsigned short* __restrict__ A, const unsigned short* __restrict__ Bt,
    const float* __restrict__ bias, float* __restrict__ C)
{
    __shared__ __align__(16) unsigned short As[128 * 32];
    __shared__ __align__(16) unsigned short Bs[128 * 32];
    gemm_body<false>(A, Bt, bias, C, M_ROWS, D_MODEL, D_MODEL, As, Bs);
}

// ---------------------------------------------------------------- MFMA flash attention
// Per block: 4 waves x 32 q-rows = 128 q. Iterate 64-key tiles with online softmax.
// S^T = K·Q^T so C-layout puts q on lane&15 (2-shuffle row stats, P-pack is A-layout).
__global__ __launch_bounds__(256) void attn_mfma(
    const unsigned short* __restrict__ Qb, const unsigned short* __restrict__ Kb,
    const unsigned short* __restrict__ Vb, unsigned short* __restrict__ ctx)
{
    constexpr int LD = 72;                    // row stride: 144B = 16B-aligned, 2-way banks max
    __shared__ __align__(16) unsigned short Ks[64 * LD];      // [key][d]
    __shared__ __align__(16) unsigned short Vt[64 * LD];      // [d][key] (transposed)
    __shared__ __align__(16) unsigned short Ps[4 * 32 * LD];  // per-wave P[q][key]

    const int tid = threadIdx.x, lane = tid & 63, wave = tid >> 6;
    const int quad = lane >> 4, l16 = lane & 15;
    const int b = blockIdx.z, h = blockIdx.y;
    const int q0 = blockIdx.x * 128 + wave * 32;
    unsigned short* Psw = Ps + wave * 32 * LD;

    // Q B-frags, held in registers for the whole kernel: B[n=q][k=d]
    short8 bq[2][2];
    #pragma unroll
    for (int nt = 0; nt < 2; ++nt)
        #pragma unroll
        for (int ks = 0; ks < 2; ++ks)
            bq[nt][ks] = *(const short8*)(Qb +
                (size_t)(b * SEQ + q0 + nt * 16 + l16) * D_MODEL + h * DEPTH + ks * 32 + quad * 8);

    f32x4 o[2][4] = {};
    float m[2] = {-1e30f, -1e30f};
    float l[2] = {0.f, 0.f};

    for (int kt = 0; kt < SEQ / 64; ++kt) {
        const size_t krow0 = (size_t)b * SEQ + kt * 64;
        // stage K tile [64 keys][64 d], coalesced 128B rows
        #pragma unroll
        for (int i = 0; i < 2; ++i) {
            int c = i * 256 + tid, r = c >> 3, c8 = c & 7;
            *(uint4*)&Ks[r * LD + c8 * 8] =
                *(const uint4*)(Kb + (krow0 + r) * D_MODEL + h * DEPTH + c8 * 8);
        }
        // stage V tile transposed -> Vt[d][key]
        {
            int key = tid & 63, dg = tid >> 6;
            const unsigned short* vs = Vb + (krow0 + key) * D_MODEL + h * DEPTH + dg * 16;
            unsigned short tmp[16];
            *(uint4*)tmp       = *(const uint4*)vs;
            *(uint4*)(tmp + 8) = *(const uint4*)(vs + 8);
            #pragma unroll
            for (int i = 0; i < 16; ++i) Vt[(dg * 16 + i) * LD + key] = tmp[i];
        }
        __syncthreads();

        // S^T[key][q] = K·Q^T : A=K[m=key][k=d], B=Q[n=q][k=d]
        f32x4 s[4][2] = {};
        #pragma unroll
        for (int mt = 0; mt < 4; ++mt)
            #pragma unroll
            for (int ks = 0; ks < 2; ++ks) {
                short8 ak = *(const short8*)&Ks[(mt * 16 + l16) * LD + ks * 32 + quad * 8];
                #pragma unroll
                for (int nt = 0; nt < 2; ++nt)
                    s[mt][nt] = __builtin_amdgcn_mfma_f32_16x16x32_bf16(ak, bq[nt][ks], s[mt][nt], 0, 0, 0);
            }

        // online softmax: frag (mt,nt) reg r -> key = mt*16+quad*4+r, q = nt*16+l16
        float rm[2] = {-1e30f, -1e30f};
        #pragma unroll
        for (int mt = 0; mt < 4; ++mt)
            #pragma unroll
            for (int nt = 0; nt < 2; ++nt)
                #pragma unroll
                for (int r = 0; r < 4; ++r) {
                    s[mt][nt][r] *= 0.125f;   // 1/sqrt(64)
                    rm[nt] = fmaxf(rm[nt], s[mt][nt][r]);
                }
        #pragma unroll
        for (int nt = 0; nt < 2; ++nt) {
            rm[nt] = fmaxf(rm[nt], __shfl_xor(rm[nt], 16));
            rm[nt] = fmaxf(rm[nt], __shfl_xor(rm[nt], 32));
        }
        float alpha[2], rs[2] = {0.f, 0.f};
        #pragma unroll
        for (int nt = 0; nt < 2; ++nt) {
            float mn = fmaxf(m[nt], rm[nt]);
            alpha[nt] = __expf(m[nt] - mn);   // first tile: exp(-1e30) = 0
            m[nt] = mn;
        }
        #pragma unroll
        for (int mt = 0; mt < 4; ++mt)
            #pragma unroll
            for (int nt = 0; nt < 2; ++nt) {
                float p0 = __expf(s[mt][nt][0] - m[nt]);
                float p1 = __expf(s[mt][nt][1] - m[nt]);
                float p2 = __expf(s[mt][nt][2] - m[nt]);
                float p3 = __expf(s[mt][nt][3] - m[nt]);
                rs[nt] += (p0 + p1) + (p2 + p3);
                ushort4 u; u.x = f2b(p0); u.y = f2b(p1); u.z = f2b(p2); u.w = f2b(p3);
                // reg r = consecutive keys -> Ps[q][key] pack (A-layout storage)
                *(ushort4*)&Psw[(nt * 16 + l16) * LD + mt * 16 + quad * 4] = u;
            }
        #pragma unroll
        for (int nt = 0; nt < 2; ++nt) {
            rs[nt] += __shfl_xor(rs[nt], 16);
            rs[nt] += __shfl_xor(rs[nt], 32);
            l[nt] = l[nt] * alpha[nt] + rs[nt];
        }
        // rescale O: frag (mq,nd) reg r -> q = mq*16+quad*4+r, alpha lives at lane q&15
        #pragma unroll
        for (int mq = 0; mq < 2; ++mq)
            #pragma unroll
            for (int r = 0; r < 4; ++r) {
                float a = __shfl(alpha[mq], quad * 4 + r);
                #pragma unroll
                for (int nd = 0; nd < 4; ++nd) o[mq][nd][r] *= a;
            }
        // PV: O[q][d] += P[q][key]·V^T : A=Ps[m=q][k=key], B=Vt[n=d][k=key]
        #pragma unroll
        for (int ks = 0; ks < 2; ++ks) {
            short8 ap[2], bv[4];
            #pragma unroll
            for (int mq = 0; mq < 2; ++mq)
                ap[mq] = *(const short8*)&Psw[(mq * 16 + l16) * LD + ks * 32 + quad * 8];
            #pragma unroll
            for (int nd = 0; nd < 4; ++nd)
                bv[nd] = *(const short8*)&Vt[(nd * 16 + l16) * LD + ks * 32 + quad * 8];
            #pragma unroll
            for (int mq = 0; mq < 2; ++mq)
                #pragma unroll
                for (int nd = 0; nd < 4; ++nd)
                    o[mq][nd] = __builtin_amdgcn_mfma_f32_16x16x32_bf16(ap[mq], bv[nd], o[mq][nd], 0, 0, 0);
        }
        __syncthreads();
    }

    float linv[2] = {1.f / l[0], 1.f / l[1]};
    #pragma unroll
    for (int mq = 0; mq < 2; ++mq)
        #pragma unroll
        for (int r = 0; r < 4; ++r) {
            float li = __shfl(linv[mq], quad * 4 + r);
            #pragma unroll
            for (int nd = 0; nd < 4; ++nd)
                ctx[(size_t)(b * SEQ + q0 + mq * 16 + quad * 4 + r) * D_MODEL +
                    h * DEPTH + nd * 16 + l16] = f2b(o[mq][nd][r] * li);
        }
}

// ---------------------------------------------------------------- launch
extern "C" void kernel_launch(void* const* d_in, const int* in_sizes, int n_in,
                              void* d_out, int out_size, void* d_ws, size_t ws_size,
                              hipStream_t stream)
{
    const float* query = (const float*)d_in[0];
    const float* key   = (const float*)d_in[1];
    const float* value = (const float*)d_in[2];
    const float* Wq = (const float*)d_in[3];
    const float* bq = (const float*)d_in[4];
    const float* Wk = (const float*)d_in[5];
    const float* bk = (const float*)d_in[6];
    const float* Wv = (const float*)d_in[7];
    const float* bv = (const float*)d_in[8];
    const float* Wo = (const float*)d_in[9];
    const float* bo = (const float*)d_in[10];

    char* ws = (char*)d_ws;
    size_t off = 0;
    auto alloc = [&](size_t bytes) -> char* {
        char* p = ws + off;
        off += (bytes + 255) & ~(size_t)255;
        return p;
    };
    const size_t xn = (size_t)M_ROWS * D_MODEL;
    unsigned short* xq   = (unsigned short*)alloc(xn * 2);
    unsigned short* xk   = (unsigned short*)alloc(xn * 2);
    unsigned short* xv   = (unsigned short*)alloc(xn * 2);
    unsigned short* wT   = (unsigned short*)alloc((size_t)3 * D_MODEL * D_MODEL * 2); // Wq^T|Wk^T|Wv^T
    unsigned short* woT  = (unsigned short*)alloc((size_t)D_MODEL * D_MODEL * 2);
    unsigned short* Qb   = (unsigned short*)alloc(xn * 2);
    unsigned short* Kb   = (unsigned short*)alloc(xn * 2);
    unsigned short* Vb   = (unsigned short*)alloc(xn * 2);
    unsigned short* ctx  = (unsigned short*)alloc(xn * 2);
    if (off > ws_size) return;

    cast3_bf16<<<dim3(4096, 3), 256, 0, stream>>>(query, key, value, xq, xk, xv);
    transpose_w<<<dim3(16, 16, 4), 256, 0, stream>>>(
        Wq, Wk, Wv, Wo,
        wT, wT + (size_t)D_MODEL * D_MODEL, wT + (size_t)2 * D_MODEL * D_MODEL, woT);
    gemm_qkv<<<dim3(8, 32, 3), 256, 0, stream>>>(xq, xk, xv, wT, bq, bk, bv, Qb, Kb, Vb);
    attn_mfma<<<dim3(SEQ / 128, NHEAD, BATCH), 256, 0, stream>>>(Qb, Kb, Vb, ctx);
    gemm_out<<<dim3(8, 32), 256, 0, stream>>>(ctx, woT, bo, (float*)d_out);
}